// Round 19
// baseline (602.350 us; speedup 1.0000x reference)
//
#include <hip/hip_runtime.h>
#include <hip/hip_cooperative_groups.h>

namespace cg = cooperative_groups;

#define NN 100000
#define NE 1000000
#define D  64
#define CAP 32          // per-node bucket capacity; Poisson(10) ⇒ P(deg>32) ≈ 2e-9/node
#define OVF_CAP 16384

#define FILL_EPT 8                                        // edges per thread
#define FILL_CHUNK (256 * FILL_EPT)                       // 2048
#define FILL_NCHUNK ((NE + FILL_CHUNK - 1) / FILL_CHUNK)  // 489
#define NFILL (FILL_NCHUNK * 8)                           // 3912 fill vblocks
#define NGAT (NN / 16)                                    // 6250 gather vblocks
#define PART_SZ 12500                                     // NN/8
#define MEGA_GRID 1024                                    // 4 blocks/CU guaranteed co-resident

// ======================= bf16 helpers (RNE pack, shift unpack) =======================
__device__ __forceinline__ unsigned bf16rne(float f) {
    unsigned h = __float_as_uint(f);
    return (h + 0x7fffu + ((h >> 16) & 1u)) >> 16;
}
__device__ __forceinline__ uint2 pack4(float4 v) {
    uint2 o;
    o.x = bf16rne(v.x) | (bf16rne(v.y) << 16);
    o.y = bf16rne(v.z) | (bf16rne(v.w) << 16);
    return o;
}
__device__ __forceinline__ float4 unpack4(uint2 u) {
    float4 f;
    f.x = __uint_as_float(u.x << 16);
    f.y = __uint_as_float(u.x & 0xffff0000u);
    f.z = __uint_as_float(u.y << 16);
    f.w = __uint_as_float(u.y & 0xffff0000u);
    return f;
}

// ======================= phase bodies (shared by mega + fallback kernels) ============

__device__ __forceinline__ void fill_vb(int vb, const int* __restrict__ src,
                                        const int* __restrict__ dst,
                                        int* __restrict__ cnt, int* __restrict__ bucket,
                                        int* __restrict__ ovf_n, int2* __restrict__ ovf) {
    const int part = vb & 7;
    const int lo = part * PART_SZ, hi = lo + PART_SZ;
    const int base = (vb >> 3) * FILL_CHUNK + threadIdx.x;
    #pragma unroll
    for (int it = 0; it < FILL_EPT; ++it) {
        int e = base + it * 256;
        if (e < NE) {
            int d = __builtin_nontemporal_load(&dst[e]);
            if (d >= lo && d < hi) {
                int s = __builtin_nontemporal_load(&src[e]);
                int c = atomicAdd(&cnt[d], 1);
                if (c < CAP) {
                    bucket[(size_t)d * CAP + c] = s;
                } else {                                 // ~never
                    int i = atomicAdd(ovf_n, 1);
                    if (i < OVF_CAP) ovf[i] = make_int2(s, d);
                }
            }
        }
    }
}

// P = bf16(x @ W^T): wave = node, lane = out col; W[lane][:] in 64 VGPRs.
__device__ __forceinline__ void cvtlinw_body(int wid, int nw, const float* __restrict__ x,
                                             const float* __restrict__ W,
                                             unsigned short* __restrict__ P) {
    const int lane = threadIdx.x & 63;
    float w[64];
    const float4* W4 = (const float4*)W;
    #pragma unroll
    for (int i = 0; i < 16; ++i) {
        float4 q = W4[lane * 16 + i];
        w[4 * i + 0] = q.x; w[4 * i + 1] = q.y;
        w[4 * i + 2] = q.z; w[4 * i + 3] = q.w;
    }
    for (int n = wid; n < NN; n += nw) {
        float xl = __builtin_nontemporal_load(&x[(size_t)n * 64 + lane]);
        int xi = __float_as_int(xl);
        float y0 = 0.f, y1 = 0.f;
        #pragma unroll
        for (int i = 0; i < 64; i += 2) {
            y0 = fmaf(__int_as_float(__builtin_amdgcn_readlane(xi, i)),     w[i],     y0);
            y1 = fmaf(__int_as_float(__builtin_amdgcn_readlane(xi, i + 1)), w[i + 1], y1);
        }
        P[(size_t)n * 64 + lane] = (unsigned short)bf16rne(y0 + y1);
    }
}

// out[n] = dinv[n]*(dinv[n]*in[n] + sum dinv[s]*in[s]); dinv = rsqrt(cnt+1) on the fly.
template <bool F32OUT>
__device__ __forceinline__ void gather_vb(int vb, const uint2* __restrict__ in2,
                                          const int* __restrict__ cnt,
                                          const int* __restrict__ bucket,
                                          const int* __restrict__ ovf_n,
                                          const int2* __restrict__ ovf,
                                          const float* __restrict__ bias,
                                          uint2* __restrict__ out2,
                                          float4* __restrict__ out4) {
    const int tid = threadIdx.x;
    const int l = tid & 15;
    const int n = vb * 16 + (tid >> 4);

    const int cn = cnt[n];
    const int deg = min(cn, CAP);
    const float dn = rsqrtf((float)(cn + 1));

    float4 a0 = unpack4(in2[(size_t)n * 16 + l]);
    a0.x *= dn; a0.y *= dn; a0.z *= dn; a0.w *= dn;
    float4 a1 = make_float4(0.f, 0.f, 0.f, 0.f);
    float4 a2 = make_float4(0.f, 0.f, 0.f, 0.f);
    float4 a3 = make_float4(0.f, 0.f, 0.f, 0.f);

    if (deg > 0) {
        int   iA = (l < deg) ? l : 0;
        int   sA = bucket[(size_t)n * CAP + iA];
        float wA = rsqrtf((float)(cnt[sA] + 1));
        const int kmax = deg < 16 ? deg : 16;
        int k = 0;
        for (; k + 3 < kmax; k += 4) {
            int   s0 = __shfl(sA, k + 0, 16);
            int   s1 = __shfl(sA, k + 1, 16);
            int   s2 = __shfl(sA, k + 2, 16);
            int   s3 = __shfl(sA, k + 3, 16);
            float w0 = __shfl(wA, k + 0, 16);
            float w1 = __shfl(wA, k + 1, 16);
            float w2 = __shfl(wA, k + 2, 16);
            float w3 = __shfl(wA, k + 3, 16);
            float4 r0 = unpack4(in2[(size_t)s0 * 16 + l]);
            float4 r1 = unpack4(in2[(size_t)s1 * 16 + l]);
            float4 r2 = unpack4(in2[(size_t)s2 * 16 + l]);
            float4 r3 = unpack4(in2[(size_t)s3 * 16 + l]);
            a0.x = fmaf(w0, r0.x, a0.x); a0.y = fmaf(w0, r0.y, a0.y);
            a0.z = fmaf(w0, r0.z, a0.z); a0.w = fmaf(w0, r0.w, a0.w);
            a1.x = fmaf(w1, r1.x, a1.x); a1.y = fmaf(w1, r1.y, a1.y);
            a1.z = fmaf(w1, r1.z, a1.z); a1.w = fmaf(w1, r1.w, a1.w);
            a2.x = fmaf(w2, r2.x, a2.x); a2.y = fmaf(w2, r2.y, a2.y);
            a2.z = fmaf(w2, r2.z, a2.z); a2.w = fmaf(w2, r2.w, a2.w);
            a3.x = fmaf(w3, r3.x, a3.x); a3.y = fmaf(w3, r3.y, a3.y);
            a3.z = fmaf(w3, r3.z, a3.z); a3.w = fmaf(w3, r3.w, a3.w);
        }
        for (; k < kmax; ++k) {
            int   s0 = __shfl(sA, k, 16);
            float w0 = __shfl(wA, k, 16);
            float4 r0 = unpack4(in2[(size_t)s0 * 16 + l]);
            a0.x = fmaf(w0, r0.x, a0.x); a0.y = fmaf(w0, r0.y, a0.y);
            a0.z = fmaf(w0, r0.z, a0.z); a0.w = fmaf(w0, r0.w, a0.w);
        }
        if (deg > 16) {   // ~3% of nodes
            int   iB = (16 + l < deg) ? (16 + l) : 0;
            int   sB = bucket[(size_t)n * CAP + iB];
            float wB = rsqrtf((float)(cnt[sB] + 1));
            const int k2max = deg - 16;
            int k2 = 0;
            for (; k2 + 1 < k2max; k2 += 2) {
                int   s0 = __shfl(sB, k2 + 0, 16);
                int   s1 = __shfl(sB, k2 + 1, 16);
                float w0 = __shfl(wB, k2 + 0, 16);
                float w1 = __shfl(wB, k2 + 1, 16);
                float4 r0 = unpack4(in2[(size_t)s0 * 16 + l]);
                float4 r1 = unpack4(in2[(size_t)s1 * 16 + l]);
                a1.x = fmaf(w0, r0.x, a1.x); a1.y = fmaf(w0, r0.y, a1.y);
                a1.z = fmaf(w0, r0.z, a1.z); a1.w = fmaf(w0, r0.w, a1.w);
                a2.x = fmaf(w1, r1.x, a2.x); a2.y = fmaf(w1, r1.y, a2.y);
                a2.z = fmaf(w1, r1.z, a2.z); a2.w = fmaf(w1, r1.w, a2.w);
            }
            if (k2 < k2max) {
                int   s0 = __shfl(sB, k2, 16);
                float w0 = __shfl(wB, k2, 16);
                float4 r0 = unpack4(in2[(size_t)s0 * 16 + l]);
                a3.x = fmaf(w0, r0.x, a3.x); a3.y = fmaf(w0, r0.y, a3.y);
                a3.z = fmaf(w0, r0.z, a3.z); a3.w = fmaf(w0, r0.w, a3.w);
            }
        }
    }

    int m = *ovf_n;   // ~always 0
    if (m > 0) {
        if (m > OVF_CAP) m = OVF_CAP;
        for (int i = 0; i < m; ++i) {
            int2 p = ovf[i];
            if (p.y == n) {
                float w = rsqrtf((float)(cnt[p.x] + 1));
                float4 r = unpack4(in2[(size_t)p.x * 16 + l]);
                a0.x = fmaf(w, r.x, a0.x); a0.y = fmaf(w, r.y, a0.y);
                a0.z = fmaf(w, r.z, a0.z); a0.w = fmaf(w, r.w, a0.w);
            }
        }
    }

    float4 r;
    r.x = dn * ((a0.x + a1.x) + (a2.x + a3.x));
    r.y = dn * ((a0.y + a1.y) + (a2.y + a3.y));
    r.z = dn * ((a0.z + a1.z) + (a2.z + a3.z));
    r.w = dn * ((a0.w + a1.w) + (a2.w + a3.w));
    if (F32OUT) {
        float4 bv = *(const float4*)&bias[4 * l];
        r.x += bv.x; r.y += bv.y; r.z += bv.z; r.w += bv.w;
        out4[(size_t)n * 16 + l] = r;
    } else {
        out2[(size_t)n * 16 + l] = pack4(r);
    }
}

// ======================= cooperative mega-kernel: all phases, 1 dispatch ============
__global__ __launch_bounds__(256, 4) void k_mega(const float* __restrict__ x,
                                                 const float* __restrict__ W,
                                                 const float* __restrict__ bias,
                                                 const int* __restrict__ src,
                                                 const int* __restrict__ dst,
                                                 int* __restrict__ cnt,
                                                 int* __restrict__ bucket,
                                                 int* __restrict__ ovf_n,
                                                 int2* __restrict__ ovf,
                                                 unsigned short* __restrict__ P,
                                                 unsigned short* __restrict__ Q,
                                                 float4* __restrict__ out) {
    cg::grid_group g = cg::this_grid();
    const int nb = gridDim.x;
    const int bid = blockIdx.x;

    // phase 0: zero cnt / ovf_n
    for (int i = bid * 256 + threadIdx.x; i < NN; i += nb * 256) cnt[i] = 0;
    if (bid == 0 && threadIdx.x == 0) *ovf_n = 0;
    g.sync();

    // phase 1: fill (grid-stride vblocks), then cvt+linW (wave-strided) — independent
    for (int vb = bid; vb < NFILL; vb += nb)
        fill_vb(vb, src, dst, cnt, bucket, ovf_n, ovf);
    {
        int wid = (bid * 256 + threadIdx.x) >> 6;
        int nw  = (nb * 256) >> 6;
        cvtlinw_body(wid, nw, x, W, P);
    }
    g.sync();

    // phase 2: hop1 P -> Q
    for (int vb = bid; vb < NGAT; vb += nb)
        gather_vb<false>(vb, (const uint2*)P, cnt, bucket, ovf_n, ovf, nullptr, (uint2*)Q, nullptr);
    g.sync();

    // phase 3: hop2 Q -> P
    for (int vb = bid; vb < NGAT; vb += nb)
        gather_vb<false>(vb, (const uint2*)Q, cnt, bucket, ovf_n, ovf, nullptr, (uint2*)P, nullptr);
    g.sync();

    // phase 4: hop3 P -> out (fp32 + bias)
    for (int vb = bid; vb < NGAT; vb += nb)
        gather_vb<true>(vb, (const uint2*)P, cnt, bucket, ovf_n, ovf, bias, nullptr, out);
}

// ======================= standalone kernels (round-18 dispatch fallback) ============

__global__ __launch_bounds__(256) void k_fill_bucket(const int* __restrict__ src,
                                                     const int* __restrict__ dst,
                                                     int* __restrict__ cnt,
                                                     int* __restrict__ bucket,
                                                     int* __restrict__ ovf_n,
                                                     int2* __restrict__ ovf) {
    fill_vb(blockIdx.x, src, dst, cnt, bucket, ovf_n, ovf);
}

__global__ __launch_bounds__(256) void k_cvt_linw(const float* __restrict__ x,
                                                  const float* __restrict__ W,
                                                  unsigned short* __restrict__ P) {
    int wid = (blockIdx.x * blockDim.x + threadIdx.x) >> 6;
    int nw  = (gridDim.x * blockDim.x) >> 6;
    cvtlinw_body(wid, nw, x, W, P);
}

__global__ __launch_bounds__(256) void k_gather_bf16(const uint2* __restrict__ in2,
                                                     const int* __restrict__ cnt,
                                                     const int* __restrict__ bucket,
                                                     const int* __restrict__ ovf_n,
                                                     const int2* __restrict__ ovf,
                                                     uint2* __restrict__ out2) {
    gather_vb<false>(blockIdx.x, in2, cnt, bucket, ovf_n, ovf, nullptr, out2, nullptr);
}

__global__ __launch_bounds__(256) void k_gather_out(const uint2* __restrict__ in2,
                                                    const int* __restrict__ cnt,
                                                    const int* __restrict__ bucket,
                                                    const int* __restrict__ ovf_n,
                                                    const int2* __restrict__ ovf,
                                                    const float* __restrict__ bias,
                                                    float4* __restrict__ out4) {
    gather_vb<true>(blockIdx.x, in2, cnt, bucket, ovf_n, ovf, bias, nullptr, out4);
}

// ======================= fallback path (atomic scatter, fp32) =======================

__global__ void k_init_deg(float* __restrict__ deg) {
    int n = blockIdx.x * blockDim.x + threadIdx.x;
    if (n < NN) deg[n] = 1.0f;
}
__global__ void k_count_deg(const int* __restrict__ dst, float* __restrict__ deg) {
    int e = blockIdx.x * blockDim.x + threadIdx.x;
    if (e < NE) atomicAdd(&deg[dst[e]], 1.0f);
}
__global__ void k_dinv_f(float* __restrict__ deg) {
    int n = blockIdx.x * blockDim.x + threadIdx.x;
    if (n < NN) deg[n] = rsqrtf(deg[n]);
}
__global__ void k_prop_init(const float* __restrict__ in, const float* __restrict__ dinv,
                            float* __restrict__ out) {
    int i = blockIdx.x * blockDim.x + threadIdx.x;
    if (i < NN * D) {
        int n = i >> 6;
        float di = dinv[n];
        out[i] = di * di * in[i];
    }
}
__global__ __launch_bounds__(256) void k_prop_edges(const float* __restrict__ in,
                                                    const int* __restrict__ src,
                                                    const int* __restrict__ dst,
                                                    const float* __restrict__ dinv,
                                                    float* __restrict__ out) {
    int t = blockIdx.x * blockDim.x + threadIdx.x;
    int e = t >> 6, f = t & 63;
    if (e < NE) {
        int s = src[e], d = dst[e];
        float w = dinv[s] * dinv[d];
        atomicAdd(&out[d * D + f], w * in[s * D + f]);
    }
}
__global__ __launch_bounds__(256) void k_linear(const float* __restrict__ in,
                                                const float* __restrict__ W,
                                                const float* __restrict__ bias,
                                                float* __restrict__ out) {
    __shared__ float Wt[64 * 65];
    __shared__ float rows[4][64];
    const int tid = threadIdx.x;
    for (int m = tid; m < 64 * 64; m += 256) {
        int o = m >> 6, i = m & 63;
        Wt[i * 65 + o] = W[m];
    }
    __syncthreads();
    const int wave = tid >> 6, lane = tid & 63;
    const float bo = bias[lane];
    for (int base = blockIdx.x * 4; base < NN; base += gridDim.x * 4) {
        int n = base + wave;
        if (n < NN) {
            rows[wave][lane] = in[n * D + lane];
            float acc = bo;
            #pragma unroll
            for (int i = 0; i < 64; ++i)
                acc = fmaf(rows[wave][i], Wt[i * 65 + lane], acc);
            out[n * D + lane] = acc;
        }
    }
}

// ======================= launch =======================

extern "C" void kernel_launch(void* const* d_in, const int* in_sizes, int n_in,
                              void* d_out, int out_size, void* d_ws, size_t ws_size,
                              hipStream_t stream) {
    const float* x   = (const float*)d_in[0];
    const int*   ei  = (const int*)d_in[1];
    const float* W   = (const float*)d_in[2];
    const float* b   = (const float*)d_in[3];
    float* out = (float*)d_out;

    const int* src = ei;        // edge_index[0]
    const int* dst = ei + NE;   // edge_index[1]

    char* ws = (char*)d_ws;
    size_t off = 0;
    auto take = [&](size_t bytes) -> char* {
        char* p = ws + off;
        off = (off + bytes + 255) & ~(size_t)255;
        return p;
    };

    int*            cnt    = (int*)take((size_t)NN * 4);
    int*            ovf_n  = (int*)take(256);
    float*          dinv   = (float*)take((size_t)NN * 4);           // fallback only
    int2*           ovf    = (int2*)take((size_t)OVF_CAP * 8);
    unsigned short* P      = (unsigned short*)take((size_t)NN * 64 * 2);  // bf16 (12.8 MB)
    unsigned short* Q      = (unsigned short*)take((size_t)NN * 64 * 2);  // bf16 (12.8 MB)
    int*            bucket = (int*)take((size_t)NN * CAP * 4);
    float*          buf    = (float*)P;   // fallback fp32 buffer spans P+Q (25.6 MB)
    const bool use_bucket = (off <= ws_size);

    const int B = 256;
    const int gridE1 = (NE + B - 1) / B;   // 3907
    const int gridN1 = (NN + B - 1) / B;   // 391

    if (use_bucket) {
        // single cooperative dispatch (all phases + zeroing inside)
        const float* xa = x; const float* Wa = W; const float* ba = b;
        const int* sa = src; const int* da = dst;
        int* ca = cnt; int* bu = bucket; int* on = ovf_n; int2* ov = ovf;
        unsigned short* Pa = P; unsigned short* Qa = Q;
        float4* oa = (float4*)out;
        void* args[] = {&xa, &Wa, &ba, &sa, &da, &ca, &bu, &on, &ov, &Pa, &Qa, &oa};
        hipError_t err = hipLaunchCooperativeKernel((const void*)k_mega, dim3(MEGA_GRID),
                                                    dim3(B), args, 0, stream);
        if (err != hipSuccess) {
            // round-18 multi-dispatch path
            size_t zlen = (size_t)((char*)ovf_n - (char*)cnt) + 256;
            (void)hipMemsetAsync(cnt, 0, zlen, stream);
            k_fill_bucket<<<NFILL, B, 0, stream>>>(src, dst, cnt, bucket, ovf_n, ovf);
            k_cvt_linw<<<2048, B, 0, stream>>>(x, W, P);
            k_gather_bf16<<<NGAT, B, 0, stream>>>((const uint2*)P, cnt, bucket, ovf_n, ovf, (uint2*)Q);
            k_gather_bf16<<<NGAT, B, 0, stream>>>((const uint2*)Q, cnt, bucket, ovf_n, ovf, (uint2*)P);
            k_gather_out<<<NGAT, B, 0, stream>>>((const uint2*)P, cnt, bucket, ovf_n, ovf, b, (float4*)out);
        }
    } else {
        const int gridF = (NN * D + B - 1) / B;
        const int gridEW = (NE * 64) / B;
        k_init_deg <<<gridN1, B, 0, stream>>>(dinv);
        k_count_deg<<<gridE1, B, 0, stream>>>(dst, dinv);
        k_dinv_f   <<<gridN1, B, 0, stream>>>(dinv);
        k_prop_init <<<gridF, B, 0, stream>>>(x, dinv, buf);
        k_prop_edges<<<gridEW, B, 0, stream>>>(x, src, dst, dinv, buf);
        k_prop_init <<<gridF, B, 0, stream>>>(buf, dinv, out);
        k_prop_edges<<<gridEW, B, 0, stream>>>(buf, src, dst, dinv, out);
        k_prop_init <<<gridF, B, 0, stream>>>(out, dinv, buf);
        k_prop_edges<<<gridEW, B, 0, stream>>>(out, src, dst, dinv, buf);
        k_linear<<<NN / 4, B, 0, stream>>>(buf, W, b, out);
    }
}

// Round 20
// 168.263 us; speedup vs baseline: 3.5798x; 3.5798x over previous
//
#include <hip/hip_runtime.h>

#define NN 100000
#define NE 1000000
#define D  64
#define CAP 32          // per-node bucket capacity; Poisson(10) ⇒ P(deg>32) ≈ 2e-9/node
#define OVF_CAP 16384

#define FILL_EPT 8                                        // edges per thread
#define FILL_CHUNK (256 * FILL_EPT)                       // 2048
#define FILL_NCHUNK ((NE + FILL_CHUNK - 1) / FILL_CHUNK)  // 489
#define PART_SZ 12500                                     // NN/8

// ======================= bf16 helpers (RNE pack, shift unpack) =======================
__device__ __forceinline__ unsigned bf16rne(float f) {
    unsigned h = __float_as_uint(f);
    return (h + 0x7fffu + ((h >> 16) & 1u)) >> 16;
}
__device__ __forceinline__ uint2 pack4(float4 v) {
    uint2 o;
    o.x = bf16rne(v.x) | (bf16rne(v.y) << 16);
    o.y = bf16rne(v.z) | (bf16rne(v.w) << 16);
    return o;
}
__device__ __forceinline__ float4 unpack4(uint2 u) {
    float4 f;
    f.x = __uint_as_float(u.x << 16);
    f.y = __uint_as_float(u.x & 0xffff0000u);
    f.z = __uint_as_float(u.y << 16);
    f.w = __uint_as_float(u.y & 0xffff0000u);
    return f;
}

// ======================= bucket build (round-10 structure: best measured) ==========
__global__ __launch_bounds__(256) void k_fill_bucket(const int* __restrict__ src,
                                                     const int* __restrict__ dst,
                                                     int* __restrict__ cnt,
                                                     int* __restrict__ bucket,
                                                     int* __restrict__ ovf_n,
                                                     int2* __restrict__ ovf) {
    const int part = blockIdx.x & 7;
    const int lo = part * PART_SZ, hi = lo + PART_SZ;
    const int base = (blockIdx.x >> 3) * FILL_CHUNK + threadIdx.x;
    #pragma unroll
    for (int it = 0; it < FILL_EPT; ++it) {
        int e = base + it * 256;
        if (e < NE) {
            int d = __builtin_nontemporal_load(&dst[e]);
            if (d >= lo && d < hi) {
                int s = __builtin_nontemporal_load(&src[e]);
                int c = atomicAdd(&cnt[d], 1);
                if (c < CAP) {
                    bucket[(size_t)d * CAP + c] = s;
                } else {                                 // ~never
                    int i = atomicAdd(ovf_n, 1);
                    if (i < OVF_CAP) ovf[i] = make_int2(s, d);
                }
            }
        }
    }
}

// ============ cvt+linear: P = bf16(x @ W^T)  (S and W commute: S^3(xW^T)=(S^3x)W^T) ====
// Runs FIRST and zeroes cnt/ovf_n (524K threads >> NN) -> memset dispatch deleted.
// wave = node, lane = output col. W[lane][:] in 64 VGPRs; x-row broadcast via readlane.
__global__ __launch_bounds__(256) void k_cvt_linw(const float* __restrict__ x,
                                                  const float* __restrict__ W,
                                                  unsigned short* __restrict__ P,
                                                  int* __restrict__ cnt,
                                                  int* __restrict__ ovf_n) {
    const int gtid = blockIdx.x * blockDim.x + threadIdx.x;
    if (gtid < NN) cnt[gtid] = 0;
    if (gtid == 0) *ovf_n = 0;

    const int lane = threadIdx.x & 63;
    const int wid  = gtid >> 6;
    const int nw   = (gridDim.x * blockDim.x) >> 6;

    float w[64];
    const float4* W4 = (const float4*)W;
    #pragma unroll
    for (int i = 0; i < 16; ++i) {
        float4 q = W4[lane * 16 + i];
        w[4 * i + 0] = q.x; w[4 * i + 1] = q.y;
        w[4 * i + 2] = q.z; w[4 * i + 3] = q.w;
    }

    for (int n = wid; n < NN; n += nw) {
        float xl = __builtin_nontemporal_load(&x[(size_t)n * 64 + lane]);
        int xi = __float_as_int(xl);
        float y0 = 0.f, y1 = 0.f;
        #pragma unroll
        for (int i = 0; i < 64; i += 2) {
            y0 = fmaf(__int_as_float(__builtin_amdgcn_readlane(xi, i)),     w[i],     y0);
            y1 = fmaf(__int_as_float(__builtin_amdgcn_readlane(xi, i + 1)), w[i + 1], y1);
        }
        P[(size_t)n * 64 + lane] = (unsigned short)bf16rne(y0 + y1);
    }
}

// ======================= propagation (pull, bf16 rows, fp32 accum, 4-deep) ==========
// out[n] = dinv[n] * ( dinv[n]*in[n] + sum_{s in N(n)} dinv[s]*in[s] ),
// dinv = rsqrt(cnt+1) on the fly. F32OUT: add bias, write fp32 (final hop).

template <bool F32OUT>
__device__ __forceinline__ void gather_body(const uint2* __restrict__ in2,
                                            const int* __restrict__ cnt,
                                            const int* __restrict__ bucket,
                                            const int* __restrict__ ovf_n,
                                            const int2* __restrict__ ovf,
                                            const float* __restrict__ bias,
                                            uint2* __restrict__ out2,
                                            float4* __restrict__ out4) {
    const int tid = threadIdx.x;
    const int l = tid & 15;
    const int n = blockIdx.x * 16 + (tid >> 4);   // 6250*16 == NN exactly

    const int cn = cnt[n];
    const int deg = min(cn, CAP);
    const float dn = rsqrtf((float)(cn + 1));

    float4 a0 = unpack4(in2[(size_t)n * 16 + l]);
    a0.x *= dn; a0.y *= dn; a0.z *= dn; a0.w *= dn;
    float4 a1 = make_float4(0.f, 0.f, 0.f, 0.f);
    float4 a2 = make_float4(0.f, 0.f, 0.f, 0.f);
    float4 a3 = make_float4(0.f, 0.f, 0.f, 0.f);

    if (deg > 0) {
        int   iA = (l < deg) ? l : 0;
        int   sA = bucket[(size_t)n * CAP + iA];
        float wA = rsqrtf((float)(cnt[sA] + 1));
        const int kmax = deg < 16 ? deg : 16;
        int k = 0;
        for (; k + 3 < kmax; k += 4) {
            int   s0 = __shfl(sA, k + 0, 16);
            int   s1 = __shfl(sA, k + 1, 16);
            int   s2 = __shfl(sA, k + 2, 16);
            int   s3 = __shfl(sA, k + 3, 16);
            float w0 = __shfl(wA, k + 0, 16);
            float w1 = __shfl(wA, k + 1, 16);
            float w2 = __shfl(wA, k + 2, 16);
            float w3 = __shfl(wA, k + 3, 16);
            float4 r0 = unpack4(in2[(size_t)s0 * 16 + l]);
            float4 r1 = unpack4(in2[(size_t)s1 * 16 + l]);
            float4 r2 = unpack4(in2[(size_t)s2 * 16 + l]);
            float4 r3 = unpack4(in2[(size_t)s3 * 16 + l]);
            a0.x = fmaf(w0, r0.x, a0.x); a0.y = fmaf(w0, r0.y, a0.y);
            a0.z = fmaf(w0, r0.z, a0.z); a0.w = fmaf(w0, r0.w, a0.w);
            a1.x = fmaf(w1, r1.x, a1.x); a1.y = fmaf(w1, r1.y, a1.y);
            a1.z = fmaf(w1, r1.z, a1.z); a1.w = fmaf(w1, r1.w, a1.w);
            a2.x = fmaf(w2, r2.x, a2.x); a2.y = fmaf(w2, r2.y, a2.y);
            a2.z = fmaf(w2, r2.z, a2.z); a2.w = fmaf(w2, r2.w, a2.w);
            a3.x = fmaf(w3, r3.x, a3.x); a3.y = fmaf(w3, r3.y, a3.y);
            a3.z = fmaf(w3, r3.z, a3.z); a3.w = fmaf(w3, r3.w, a3.w);
        }
        for (; k < kmax; ++k) {
            int   s0 = __shfl(sA, k, 16);
            float w0 = __shfl(wA, k, 16);
            float4 r0 = unpack4(in2[(size_t)s0 * 16 + l]);
            a0.x = fmaf(w0, r0.x, a0.x); a0.y = fmaf(w0, r0.y, a0.y);
            a0.z = fmaf(w0, r0.z, a0.z); a0.w = fmaf(w0, r0.w, a0.w);
        }
        if (deg > 16) {   // ~3% of nodes
            int   iB = (16 + l < deg) ? (16 + l) : 0;
            int   sB = bucket[(size_t)n * CAP + iB];
            float wB = rsqrtf((float)(cnt[sB] + 1));
            const int k2max = deg - 16;
            int k2 = 0;
            for (; k2 + 1 < k2max; k2 += 2) {
                int   s0 = __shfl(sB, k2 + 0, 16);
                int   s1 = __shfl(sB, k2 + 1, 16);
                float w0 = __shfl(wB, k2 + 0, 16);
                float w1 = __shfl(wB, k2 + 1, 16);
                float4 r0 = unpack4(in2[(size_t)s0 * 16 + l]);
                float4 r1 = unpack4(in2[(size_t)s1 * 16 + l]);
                a1.x = fmaf(w0, r0.x, a1.x); a1.y = fmaf(w0, r0.y, a1.y);
                a1.z = fmaf(w0, r0.z, a1.z); a1.w = fmaf(w0, r0.w, a1.w);
                a2.x = fmaf(w1, r1.x, a2.x); a2.y = fmaf(w1, r1.y, a2.y);
                a2.z = fmaf(w1, r1.z, a2.z); a2.w = fmaf(w1, r1.w, a2.w);
            }
            if (k2 < k2max) {
                int   s0 = __shfl(sB, k2, 16);
                float w0 = __shfl(wB, k2, 16);
                float4 r0 = unpack4(in2[(size_t)s0 * 16 + l]);
                a3.x = fmaf(w0, r0.x, a3.x); a3.y = fmaf(w0, r0.y, a3.y);
                a3.z = fmaf(w0, r0.z, a3.z); a3.w = fmaf(w0, r0.w, a3.w);
            }
        }
    }

    // inline overflow fixup (ovf_n is ~always 0; one hot scalar load)
    int m = *ovf_n;
    if (m > 0) {
        if (m > OVF_CAP) m = OVF_CAP;
        for (int i = 0; i < m; ++i) {
            int2 p = ovf[i];
            if (p.y == n) {
                float w = rsqrtf((float)(cnt[p.x] + 1));
                float4 r = unpack4(in2[(size_t)p.x * 16 + l]);
                a0.x = fmaf(w, r.x, a0.x); a0.y = fmaf(w, r.y, a0.y);
                a0.z = fmaf(w, r.z, a0.z); a0.w = fmaf(w, r.w, a0.w);
            }
        }
    }

    float4 r;
    r.x = dn * ((a0.x + a1.x) + (a2.x + a3.x));
    r.y = dn * ((a0.y + a1.y) + (a2.y + a3.y));
    r.z = dn * ((a0.z + a1.z) + (a2.z + a3.z));
    r.w = dn * ((a0.w + a1.w) + (a2.w + a3.w));
    if (F32OUT) {
        float4 bv = *(const float4*)&bias[4 * l];
        r.x += bv.x; r.y += bv.y; r.z += bv.z; r.w += bv.w;
        out4[(size_t)n * 16 + l] = r;
    } else {
        out2[(size_t)n * 16 + l] = pack4(r);
    }
}

__global__ __launch_bounds__(256) void k_gather_bf16(const uint2* __restrict__ in2,
                                                     const int* __restrict__ cnt,
                                                     const int* __restrict__ bucket,
                                                     const int* __restrict__ ovf_n,
                                                     const int2* __restrict__ ovf,
                                                     uint2* __restrict__ out2) {
    gather_body<false>(in2, cnt, bucket, ovf_n, ovf, nullptr, out2, nullptr);
}

__global__ __launch_bounds__(256) void k_gather_out(const uint2* __restrict__ in2,
                                                    const int* __restrict__ cnt,
                                                    const int* __restrict__ bucket,
                                                    const int* __restrict__ ovf_n,
                                                    const int2* __restrict__ ovf,
                                                    const float* __restrict__ bias,
                                                    float4* __restrict__ out4) {
    gather_body<true>(in2, cnt, bucket, ovf_n, ovf, bias, nullptr, out4);
}

// ======================= fallback path (atomic scatter, fp32) =======================

__global__ void k_init_deg(float* __restrict__ deg) {
    int n = blockIdx.x * blockDim.x + threadIdx.x;
    if (n < NN) deg[n] = 1.0f;
}
__global__ void k_count_deg(const int* __restrict__ dst, float* __restrict__ deg) {
    int e = blockIdx.x * blockDim.x + threadIdx.x;
    if (e < NE) atomicAdd(&deg[dst[e]], 1.0f);
}
__global__ void k_dinv_f(float* __restrict__ deg) {
    int n = blockIdx.x * blockDim.x + threadIdx.x;
    if (n < NN) deg[n] = rsqrtf(deg[n]);
}
__global__ void k_prop_init(const float* __restrict__ in, const float* __restrict__ dinv,
                            float* __restrict__ out) {
    int i = blockIdx.x * blockDim.x + threadIdx.x;
    if (i < NN * D) {
        int n = i >> 6;
        float di = dinv[n];
        out[i] = di * di * in[i];
    }
}
__global__ __launch_bounds__(256) void k_prop_edges(const float* __restrict__ in,
                                                    const int* __restrict__ src,
                                                    const int* __restrict__ dst,
                                                    const float* __restrict__ dinv,
                                                    float* __restrict__ out) {
    int t = blockIdx.x * blockDim.x + threadIdx.x;
    int e = t >> 6, f = t & 63;
    if (e < NE) {
        int s = src[e], d = dst[e];
        float w = dinv[s] * dinv[d];
        atomicAdd(&out[d * D + f], w * in[s * D + f]);
    }
}
__global__ __launch_bounds__(256) void k_linear(const float* __restrict__ in,
                                                const float* __restrict__ W,
                                                const float* __restrict__ bias,
                                                float* __restrict__ out) {
    __shared__ float Wt[64 * 65];
    __shared__ float rows[4][64];
    const int tid = threadIdx.x;
    for (int m = tid; m < 64 * 64; m += 256) {
        int o = m >> 6, i = m & 63;
        Wt[i * 65 + o] = W[m];
    }
    __syncthreads();
    const int wave = tid >> 6, lane = tid & 63;
    const float bo = bias[lane];
    for (int base = blockIdx.x * 4; base < NN; base += gridDim.x * 4) {
        int n = base + wave;
        if (n < NN) {
            rows[wave][lane] = in[n * D + lane];
            float acc = bo;
            #pragma unroll
            for (int i = 0; i < 64; ++i)
                acc = fmaf(rows[wave][i], Wt[i * 65 + lane], acc);
            out[n * D + lane] = acc;
        }
    }
}

// ======================= launch =======================

extern "C" void kernel_launch(void* const* d_in, const int* in_sizes, int n_in,
                              void* d_out, int out_size, void* d_ws, size_t ws_size,
                              hipStream_t stream) {
    const float* x   = (const float*)d_in[0];
    const int*   ei  = (const int*)d_in[1];
    const float* W   = (const float*)d_in[2];
    const float* b   = (const float*)d_in[3];
    float* out = (float*)d_out;

    const int* src = ei;        // edge_index[0]
    const int* dst = ei + NE;   // edge_index[1]

    char* ws = (char*)d_ws;
    size_t off = 0;
    auto take = [&](size_t bytes) -> char* {
        char* p = ws + off;
        off = (off + bytes + 255) & ~(size_t)255;
        return p;
    };

    int*            cnt    = (int*)take((size_t)NN * 4);
    int*            ovf_n  = (int*)take(256);
    float*          dinv   = (float*)take((size_t)NN * 4);           // fallback only
    int2*           ovf    = (int2*)take((size_t)OVF_CAP * 8);
    unsigned short* P      = (unsigned short*)take((size_t)NN * 64 * 2);  // bf16 (12.8 MB)
    unsigned short* Q      = (unsigned short*)take((size_t)NN * 64 * 2);  // bf16 (12.8 MB)
    int*            bucket = (int*)take((size_t)NN * CAP * 4);
    float*          buf    = (float*)P;   // fallback fp32 buffer spans P+Q (25.6 MB)
    const bool use_bucket = (off <= ws_size);

    const int B = 256;
    const int gridE1 = (NE + B - 1) / B;   // 3907
    const int gridN1 = (NN + B - 1) / B;   // 391
    const int gridNW = NN / 16;            // 6250

    if (use_bucket) {
        // cvt+linW first (also zeroes cnt/ovf_n -> no memset dispatch)
        k_cvt_linw<<<2048, B, 0, stream>>>(x, W, P, cnt, ovf_n);
        k_fill_bucket<<<FILL_NCHUNK * 8, B, 0, stream>>>(src, dst, cnt, bucket, ovf_n, ovf);
        // hop1: P -> Q
        k_gather_bf16<<<gridNW, B, 0, stream>>>((const uint2*)P, cnt, bucket, ovf_n, ovf, (uint2*)Q);
        // hop2: Q -> P
        k_gather_bf16<<<gridNW, B, 0, stream>>>((const uint2*)Q, cnt, bucket, ovf_n, ovf, (uint2*)P);
        // hop3: P -> out (fp32, + bias)
        k_gather_out<<<gridNW, B, 0, stream>>>((const uint2*)P, cnt, bucket, ovf_n, ovf, b, (float4*)out);
    } else {
        const int gridF = (NN * D + B - 1) / B;
        const int gridEW = (NE * 64) / B;
        k_init_deg <<<gridN1, B, 0, stream>>>(dinv);
        k_count_deg<<<gridE1, B, 0, stream>>>(dst, dinv);
        k_dinv_f   <<<gridN1, B, 0, stream>>>(dinv);
        k_prop_init <<<gridF, B, 0, stream>>>(x, dinv, buf);
        k_prop_edges<<<gridEW, B, 0, stream>>>(x, src, dst, dinv, buf);
        k_prop_init <<<gridF, B, 0, stream>>>(buf, dinv, out);
        k_prop_edges<<<gridEW, B, 0, stream>>>(buf, src, dst, dinv, out);
        k_prop_init <<<gridF, B, 0, stream>>>(out, dinv, buf);
        k_prop_edges<<<gridEW, B, 0, stream>>>(out, src, dst, dinv, buf);
        k_linear<<<NN / 4, B, 0, stream>>>(buf, W, b, out);
    }
}